// Round 7
// baseline (640.062 us; speedup 1.0000x reference)
//
#include <hip/hip_runtime.h>
#include <hip/hip_bf16.h>
#include <stdint.h>
#include <stdio.h>

// Problem sizes (fixed by setup_inputs)
#define B_ 4
#define S_ 2048
#define D_ 2048
#define P_ 2729
#define NP 2816            // P padded to multiple of 256
#define M_ (B_ * S_)       // 8192

#define SCHUNK 128
#define NCHUNK (S_ / SCHUNK)   // 16

typedef __attribute__((ext_vector_type(8))) short bh8;   // 8 x bf16 (4 VGPRs)
typedef __attribute__((ext_vector_type(4))) float fx4;   // MFMA accumulator

static __device__ __forceinline__ float bf2f(unsigned short u) {
  union { unsigned int i; float f; } c;
  c.i = ((unsigned int)u) << 16;
  return c.f;
}
static __device__ __forceinline__ unsigned short f2bf(float f) {
  union { __hip_bfloat16 h; unsigned short u; } c;
  c.h = __float2bfloat16(f);
  return c.u;
}
static __device__ __forceinline__ float fast_tanh(float x) {
  return 1.0f - 2.0f / (__expf(2.0f * x) + 1.0f);
}
static __device__ __forceinline__ float gate_act(float z) {
  float sc = 15.0f * fast_tanh(z * (1.0f / 15.0f));
  return 1.0f / (1.0f + __expf(-sc));
}

static __device__ __forceinline__ void gload_lds16(const ushort* g, ushort* l) {
  __builtin_amdgcn_global_load_lds(
      (const __attribute__((address_space(1))) unsigned int*)g,
      (__attribute__((address_space(3))) unsigned int*)l, 16, 0, 0);
}

// ---------------- RMSNorm + bf16 cast ----------------
__global__ __launch_bounds__(256) void rmsnorm_kernel(const float* __restrict__ x,
                                                      const float* __restrict__ w,
                                                      __hip_bfloat16* __restrict__ xn) {
  int row = blockIdx.x;
  const float4* xr = (const float4*)(x + (size_t)row * D_);
  int t = threadIdx.x;
  float4 v0 = xr[t];
  float4 v1 = xr[t + 256];
  float ss = v0.x * v0.x + v0.y * v0.y + v0.z * v0.z + v0.w * v0.w +
             v1.x * v1.x + v1.y * v1.y + v1.z * v1.z + v1.w * v1.w;
#pragma unroll
  for (int off = 32; off > 0; off >>= 1) ss += __shfl_down(ss, off);
  __shared__ float red[4];
  if ((t & 63) == 0) red[t >> 6] = ss;
  __syncthreads();
  float scale = rsqrtf((red[0] + red[1] + red[2] + red[3]) * (1.0f / (float)D_) + 1e-6f);
  const float4* wp = (const float4*)w;
  float4 w0 = wp[t], w1 = wp[t + 256];
  ushort4 o0, o1;
  o0.x = f2bf(v0.x * scale * w0.x);
  o0.y = f2bf(v0.y * scale * w0.y);
  o0.z = f2bf(v0.z * scale * w0.z);
  o0.w = f2bf(v0.w * scale * w0.w);
  o1.x = f2bf(v1.x * scale * w1.x);
  o1.y = f2bf(v1.y * scale * w1.y);
  o1.z = f2bf(v1.z * scale * w1.z);
  o1.w = f2bf(v1.w * scale * w1.w);
  ushort4* xo = (ushort4*)(xn + (size_t)row * D_);
  xo[t] = o0;
  xo[t + 256] = o1;
}

// ---------------- weight conversion ----------------
__global__ __launch_bounds__(256) void convert_gate_w(const float* __restrict__ Wi,
                                                      const float* __restrict__ Wf,
                                                      const float* __restrict__ Wo,
                                                      const float* __restrict__ Wc,
                                                      __hip_bfloat16* __restrict__ Wb) {
  int g = blockIdx.z;
  const float* W = (g == 0) ? Wi : (g == 1) ? Wf : (g == 2) ? Wo : Wc;
  size_t u = (size_t)blockIdx.x * 256 + threadIdx.x;  // float4 index, NP*512 per gate
  int j = (int)(u >> 9);
  int q = (int)(u & 511);
  ushort4 o;
  if (j < P_) {
    float4 v = ((const float4*)(W + (size_t)j * D_))[q];
    o.x = f2bf(v.x); o.y = f2bf(v.y); o.z = f2bf(v.z); o.w = f2bf(v.w);
  } else {
    o.x = 0; o.y = 0; o.z = 0; o.w = 0;
  }
  ushort4* dst = (ushort4*)(Wb + (size_t)g * NP * D_ + (size_t)j * D_ + (size_t)q * 4);
  *dst = o;
}

__global__ __launch_bounds__(256) void convert_wout(const float* __restrict__ Wout,
                                                    __hip_bfloat16* __restrict__ Woutb) {
  size_t u = (size_t)blockIdx.x * 256 + threadIdx.x;
  if (u >= (size_t)D_ * NP) return;
  int d = (int)(u / NP);
  int p = (int)(u - (size_t)d * NP);
  float v = (p < P_) ? Wout[(size_t)d * P_ + p] : 0.0f;
  Woutb[u] = __float2bfloat16(v);
}

// ---------------- GEMM core (C = A*B^T), bf16, 256x256 tile, BK=32, 4-deep dbuf ----------------
// 512 threads = 8 waves (2M x 4N); per-wave output 128x64.
// LDS: 4 buffer-pairs of (A[256][32] + B[256][32]) bf16 = 32 KB each, 128 KB.
// Packed layout: 2 M-rows per 128B LDS row (rho = m>>1); logical 16B slot
// lambda = (m&1)*4 + kslot stored at physical slot lambda ^ (rho&7).
// Reads are 2 lanes/slot per 16-lane phase = conflict-free. gload_lds dest is
// LINEAR; the swizzle is pre-applied to the GLOBAL source address (rule #21).
// Counted-vmcnt pipeline (T4): stage k+96 while computing k; per iter
// {STAGE; COMPUTE; vmcnt(8); s_barrier} -- never vmcnt(0) in the main loop.
// Ledger (per-wave instrs): prologue 12, vmcnt(8)->buf0 done; steady issue 4,
// drain 4, vmcnt(8) completes exactly buf[k+32] (issued 2 phases earlier).
// Write hazard: stage target buf[k-32] was last ds_read in the previous phase;
// reads complete before that phase's MFMAs (lgkmcnt) hence before its barrier.
template <int LD, int KTOT>
static __device__ __forceinline__ void gemm_core(const ushort* __restrict__ A,
                                                 const ushort* __restrict__ Bm,
                                                 int tile_m, int tile_n,
                                                 ushort* lds,   // 65536 ushorts
                                                 fx4 (&acc)[8][4]) {
  const int t = threadIdx.x;       // 0..511
  const int lane = t & 63;
  const int w = t >> 6;            // 0..7
  const int wr = w >> 2, wc = w & 3;
  const int frow = lane & 15;
  const int g = lane >> 4;

  // ---- staging precompute: 4 gload_lds per thread per K32-step ----
  // u = q*512 + t in [0,2048): u<1024 -> A, else B. Within matrix:
  // rho = uu>>3, pi = uu&7, lambda = pi ^ (rho&7), m = 2*rho + (lambda>>2),
  // kslot = lambda&3. LDS dest linear at uu*8 elems (A) / 8192+uu*8 (B).
  const ushort* gsrc[4];
  int loff[4];
#pragma unroll
  for (int q = 0; q < 4; ++q) {
    int u = q * 512 + t;
    int isB = u >> 10;
    int uu = u & 1023;
    int rho = uu >> 3;
    int pi = uu & 7;
    int lam = pi ^ (rho & 7);
    int row = 2 * rho + (lam >> 2);
    int kslot = lam & 3;
    gsrc[q] = (isB ? (Bm + (size_t)(tile_n + row) * LD)
                   : (A + (size_t)(tile_m + row) * LD)) + kslot * 8;
    loff[q] = isB * 8192 + uu * 8;
  }

  auto STAGE = [&](int k0, int bi) {
    ushort* pair = lds + (bi << 14);
#pragma unroll
    for (int q = 0; q < 4; ++q) gload_lds16(gsrc[q] + k0, pair + loff[q]);
  };

  // ---- read addressing (bytes within a pair) ----
  // A frag (mf): byte = (wr*64 + mf*8 + (frow>>1))*128 + pix
  // B frag (nf): byte = 16384 + (wc*32 + nf*8 + (frow>>1))*128 + pix
  const int pix = ((((frow & 1) << 2) | g) ^ ((frow >> 1) & 7)) << 4;
  const int aBase = (wr * 64 + (frow >> 1)) << 7;
  const int bBase = 16384 + ((wc * 32 + (frow >> 1)) << 7);

  auto COMPUTE = [&](int bi) {
    const char* pair = (const char*)(lds + (bi << 14));
    bh8 bf[4];
#pragma unroll
    for (int nf = 0; nf < 4; ++nf)
      bf[nf] = *(const bh8*)(pair + bBase + (nf << 10) + pix);
    bh8 af[8];
#pragma unroll
    for (int mf = 0; mf < 8; ++mf)
      af[mf] = *(const bh8*)(pair + aBase + (mf << 10) + pix);
#pragma unroll
    for (int mf = 0; mf < 8; ++mf)
#pragma unroll
      for (int nf = 0; nf < 4; ++nf)
        acc[mf][nf] = __builtin_amdgcn_mfma_f32_16x16x32_bf16(af[mf], bf[nf], acc[mf][nf], 0, 0, 0);
  };

  // ---- prologue: fill bufs 0,1,2; wait for buf0 only ----
  STAGE(0, 0);
  STAGE(32, 1);
  STAGE(64, 2);
  asm volatile("s_waitcnt vmcnt(8)" ::: "memory");
  __builtin_amdgcn_s_barrier();

  // ---- main loop: 3-deep prefetch, counted vmcnt ----
  for (int k0 = 0; k0 + 96 < KTOT; k0 += 32) {
    const int bi = (k0 >> 5) & 3;
    STAGE(k0 + 96, (bi + 3) & 3);
    COMPUTE(bi);
    asm volatile("s_waitcnt vmcnt(8)" ::: "memory");
    __builtin_amdgcn_s_barrier();
  }
  // ---- tail: k = KTOT-96, KTOT-64, KTOT-32 ----
  {
    const int b0 = ((KTOT - 96) >> 5) & 3;
    COMPUTE(b0);
    asm volatile("s_waitcnt vmcnt(4)" ::: "memory");
    __builtin_amdgcn_s_barrier();
    COMPUTE((b0 + 1) & 3);
    asm volatile("s_waitcnt vmcnt(0)" ::: "memory");
    __builtin_amdgcn_s_barrier();
    COMPUTE((b0 + 2) & 3);
  }
}

// Gate GEMM: gates[g][m][n] = act(sum_d xn[m][d] * Wb[g][n][d])
__global__ __launch_bounds__(512, 2) void gemm_gates(const __hip_bfloat16* __restrict__ A,
                                                     const __hip_bfloat16* __restrict__ Wb,
                                                     __hip_bfloat16* __restrict__ G) {
  __shared__ ushort lds[4 * 16384];  // 128 KiB
  int gate = blockIdx.z;
  // XCD band order: xcd = lin&7 owns 4 consecutive by-rows (A-slice 4 MB = L2);
  // bx outer, by inner.
  int lin = blockIdx.x + 11 * blockIdx.y;   // 0..351
  int xcd = lin & 7;
  int idx = lin >> 3;                       // 0..43
  int bx = idx % 11;
  int by = xcd * 4 + idx / 11;              // 0..31
  int tile_n = bx * 256;
  int tile_m = by * 256;

  const ushort* Bm = (const ushort*)Wb + (size_t)gate * NP * D_;
  __hip_bfloat16* Gg = G + (size_t)gate * M_ * NP;

  fx4 acc[8][4];
#pragma unroll
  for (int i = 0; i < 8; ++i)
#pragma unroll
    for (int j = 0; j < 4; ++j) acc[i][j] = (fx4){0.f, 0.f, 0.f, 0.f};

  gemm_core<D_, D_>((const ushort*)A, Bm, tile_m, tile_n, lds, acc);

  int lane = threadIdx.x & 63;
  int w = threadIdx.x >> 6;
  int wr = w >> 2, wc = w & 3;
  int g = lane >> 4;
#pragma unroll
  for (int mf = 0; mf < 8; ++mf) {
    int mbase = tile_m + wr * 128 + mf * 16 + (g << 2);
#pragma unroll
    for (int nf = 0; nf < 4; ++nf) {
      int n = tile_n + wc * 64 + nf * 16 + (lane & 15);
      bool valid = (n < P_);
#pragma unroll
      for (int r = 0; r < 4; ++r) {
        float z = acc[mf][nf][r];
        float val = (gate == 3) ? fast_tanh(z) : gate_act(z);
        if (!valid) val = 0.0f;
        Gg[(size_t)(mbase + r) * NP + n] = __float2bfloat16(val);
      }
    }
  }
}

// Output GEMM: out[m][n] = x[m][n] + sum_p outbuf[m][p] * Woutb[n][p]
__global__ __launch_bounds__(512, 2) void gemm_out(const __hip_bfloat16* __restrict__ A,
                                                   const __hip_bfloat16* __restrict__ Bw,
                                                   const float* __restrict__ X,
                                                   float* __restrict__ Out) {
  __shared__ ushort lds[4 * 16384];
  // XCD band order: grid 8 x 32; xcd owns 4 by-rows, bx outer / by inner
  int lin = blockIdx.x + 8 * blockIdx.y;    // 0..255
  int xcd = lin & 7;
  int idx = lin >> 3;                       // 0..31
  int bx = idx & 7;
  int by = xcd * 4 + (idx >> 3);            // 0..31
  int tile_n = bx * 256;
  int tile_m = by * 256;

  fx4 acc[8][4];
#pragma unroll
  for (int i = 0; i < 8; ++i)
#pragma unroll
    for (int j = 0; j < 4; ++j) acc[i][j] = (fx4){0.f, 0.f, 0.f, 0.f};

  gemm_core<NP, NP>((const ushort*)A, (const ushort*)Bw, tile_m, tile_n, lds, acc);

  int lane = threadIdx.x & 63;
  int w = threadIdx.x >> 6;
  int wr = w >> 2, wc = w & 3;
  int g = lane >> 4;
#pragma unroll
  for (int mf = 0; mf < 8; ++mf) {
    int mbase = tile_m + wr * 128 + mf * 16 + (g << 2);
#pragma unroll
    for (int nf = 0; nf < 4; ++nf) {
      int n = tile_n + wc * 64 + nf * 16 + (lane & 15);
#pragma unroll
      for (int r = 0; r < 4; ++r) {
        size_t o = (size_t)(mbase + r) * D_ + n;
        Out[o] = X[o] + acc[mf][nf][r];
      }
    }
  }
}

// ---------------- chunked parallel LSTM scan (h = f*h + u is linear in h) ----------------
__global__ __launch_bounds__(256) void scan_pass1(const __hip_bfloat16* __restrict__ G,
                                                  float* __restrict__ Aa, float* __restrict__ Bb) {
  int idx = blockIdx.x * 256 + threadIdx.x;  // (b,p) flat
  int c = blockIdx.y;
  int b = idx / NP, p = idx - b * NP;
  size_t base = ((size_t)(b * S_ + c * SCHUNK)) * NP + p;
  const unsigned short* gi = (const unsigned short*)G + base;
  const size_t gs = (size_t)M_ * NP;
  const unsigned short* gf = gi + gs;
  const unsigned short* gc = gi + 3 * gs;
  float a = 1.f, acc = 0.f;
#pragma unroll 8
  for (int s = 0; s < SCHUNK; ++s) {
    size_t off = (size_t)s * NP;
    float fv = bf2f(gf[off]);
    float u = bf2f(gi[off]) * bf2f(gc[off]);
    acc = fv * acc + u;
    a *= fv;
  }
  int o = c * (B_ * NP) + idx;
  Aa[o] = a;
  Bb[o] = acc;
}

__global__ __launch_bounds__(256) void scan_mid(const float* __restrict__ Aa,
                                                const float* __restrict__ Bb,
                                                const float* __restrict__ h0,
                                                float* __restrict__ Hs,
                                                float* __restrict__ hfin) {
  int idx = blockIdx.x * 256 + threadIdx.x;
  int b = idx / NP, p = idx - b * NP;
  float h = (p < P_) ? h0[b * P_ + p] : 0.f;
#pragma unroll
  for (int c = 0; c < NCHUNK; ++c) {
    int o = c * (B_ * NP) + idx;
    Hs[o] = h;
    h = Aa[o] * h + Bb[o];
  }
  if (p < P_) hfin[b * P_ + p] = h;
}

__global__ __launch_bounds__(256) void scan_pass2(const __hip_bfloat16* __restrict__ G,
                                                  const float* __restrict__ Hs,
                                                  __hip_bfloat16* __restrict__ outb) {
  int idx = blockIdx.x * 256 + threadIdx.x;
  int c = blockIdx.y;
  int b = idx / NP, p = idx - b * NP;
  size_t base = ((size_t)(b * S_ + c * SCHUNK)) * NP + p;
  const unsigned short* gi = (const unsigned short*)G + base;
  const size_t gs = (size_t)M_ * NP;
  const unsigned short* gf = gi + gs;
  const unsigned short* go = gi + 2 * gs;
  const unsigned short* gc = gi + 3 * gs;
  unsigned short* ob = (unsigned short*)outb + base;
  float h = Hs[c * (B_ * NP) + idx];
#pragma unroll 4
  for (int s = 0; s < SCHUNK; ++s) {
    size_t off = (size_t)s * NP;
    float u = bf2f(gi[off]) * bf2f(gc[off]);
    h = bf2f(gf[off]) * h + u;
    ob[off] = f2bf(bf2f(go[off]) * fast_tanh(h));
  }
}

// ---------------- launch ----------------
extern "C" void kernel_launch(void* const* d_in, const int* in_sizes, int n_in,
                              void* d_out, int out_size, void* d_ws, size_t ws_size,
                              hipStream_t stream) {
  const float* x    = (const float*)d_in[0];
  const float* h0   = (const float*)d_in[1];
  const float* Wi   = (const float*)d_in[2];
  const float* Wf   = (const float*)d_in[3];
  const float* Wo   = (const float*)d_in[4];
  const float* Wc   = (const float*)d_in[5];
  const float* Wout = (const float*)d_in[6];
  const float* lnw  = (const float*)d_in[7];
  float* out  = (float*)d_out;
  float* hfin = out + (size_t)M_ * D_;

  const size_t wb_off    = (size_t)M_ * D_;                    // 16,777,216
  const size_t gates_off = wb_off + (size_t)4 * NP * D_;       // 39,845,888
  const size_t need = (gates_off + (size_t)4 * M_ * NP) * 2;   // bytes
  if (ws_size < need) {
    fprintf(stderr, "kernel_launch: ws too small (%zu < %zu)\n", ws_size, need);
    return;
  }
  __hip_bfloat16* ws     = (__hip_bfloat16*)d_ws;
  __hip_bfloat16* xn     = ws;
  __hip_bfloat16* Wb     = ws + wb_off;
  __hip_bfloat16* Gg     = ws + gates_off;
  __hip_bfloat16* outbuf = ws;                                  // aliases xn/Wb (dead)
  __hip_bfloat16* Woutb  = ws + (size_t)M_ * NP;
  float* scr = (float*)(ws + (size_t)M_ * NP + (size_t)D_ * NP);
  float* Aa = scr;
  float* Bb = Aa + NCHUNK * B_ * NP;
  float* Hs = Bb + NCHUNK * B_ * NP;

  convert_gate_w<<<dim3(NP * 512 / 256, 1, 4), 256, 0, stream>>>(Wi, Wf, Wo, Wc, Wb);
  rmsnorm_kernel<<<M_, 256, 0, stream>>>(x, lnw, xn);
  gemm_gates<<<dim3(NP / 256, M_ / 256, 4), 512, 0, stream>>>(xn, Wb, Gg);
  convert_wout<<<(int)(((size_t)D_ * NP + 255) / 256), 256, 0, stream>>>(Wout, Woutb);
  scan_pass1<<<dim3(B_ * NP / 256, NCHUNK), 256, 0, stream>>>(Gg, Aa, Bb);
  scan_mid<<<B_ * NP / 256, 256, 0, stream>>>(Aa, Bb, h0, Hs, hfin);
  scan_pass2<<<dim3(B_ * NP / 256, NCHUNK), 256, 0, stream>>>(Gg, Hs, outbuf);
  gemm_out<<<dim3(D_ / 256, M_ / 256), 512, 0, stream>>>(outbuf, Woutb, x, out);
}